// Round 4
// baseline (1192.323 us; speedup 1.0000x reference)
//
#include <hip/hip_runtime.h>
#include <hip/hip_fp16.h>
#include <math.h>

#define U_NUM 100000
#define I_NUM 50000
#define NE    2000000
#define EMB   64
#define NLAYERS 3

// bucketing: 128 rows per bucket
#define BSH   7
#define NBU_U ((U_NUM + 127) >> 7)   // 782
#define NBU_I ((I_NUM + 127) >> 7)   // 391
#define CHUNK 2048
#define NBLK_E ((NE + CHUNK - 1) / CHUNK)
#define DBINS 512

static inline int ceil_div(int a, int b){ return (a + b - 1) / b; }

// ---------------- phase 1: bucket partition ----------------

__global__ void bucket_hist_k(const int* __restrict__ u_idx, const int* __restrict__ i_idx,
                              int* __restrict__ bcnt_u, int* __restrict__ bcnt_i){
  __shared__ int hU[NBU_U];
  __shared__ int hI[NBU_I];
  for (int t = threadIdx.x; t < NBU_U; t += 256) hU[t] = 0;
  for (int t = threadIdx.x; t < NBU_I; t += 256) hI[t] = 0;
  __syncthreads();
  int base = blockIdx.x * CHUNK;
  int end = min(base + CHUNK, NE);
  // base/end always even (NE even, CHUNK even) -> int2 pairs safe
  for (int e = base + (threadIdx.x << 1); e < end; e += 512){
    int2 uu = *(const int2*)(u_idx + e);
    int2 ii = *(const int2*)(i_idx + e);
    atomicAdd(&hU[uu.x >> BSH], 1);
    atomicAdd(&hU[uu.y >> BSH], 1);
    atomicAdd(&hI[ii.x >> BSH], 1);
    atomicAdd(&hI[ii.y >> BSH], 1);
  }
  __syncthreads();
  for (int t = threadIdx.x; t < NBU_U; t += 256) if (hU[t]) atomicAdd(&bcnt_u[t], hU[t]);
  for (int t = threadIdx.x; t < NBU_I; t += 256) if (hI[t]) atomicAdd(&bcnt_i[t], hI[t]);
}

// single-block exclusive scan, n <= 1024; writes offs[0..n] and cur=offs
__global__ void small_scan_k(const int* __restrict__ cnt, int* __restrict__ offs,
                             int* __restrict__ cur, int n){
  __shared__ int s[1024];
  int t = threadIdx.x;
  int v = (t < n) ? cnt[t] : 0;
  s[t] = v; __syncthreads();
  for (int o = 1; o < 1024; o <<= 1){
    int x = (t >= o) ? s[t - o] : 0;
    __syncthreads();
    s[t] += x;
    __syncthreads();
  }
  int excl = (t > 0) ? s[t - 1] : 0;
  if (t < n){ offs[t] = excl; cur[t] = excl; }
  if (t == n - 1) offs[n] = s[t];
}

// packed bin entry: (row_local << 24) | neighbor   (row_local < 128, neighbor < 2^17)
__global__ void binfill_k(const int* __restrict__ u_idx, const int* __restrict__ i_idx,
                          int* __restrict__ bcur_u, int* __restrict__ bcur_i,
                          int* __restrict__ bin_u, int* __restrict__ bin_i){
  __shared__ int hU[NBU_U];
  __shared__ int hI[NBU_I];
  __shared__ int baU[NBU_U];
  __shared__ int baI[NBU_I];
  for (int t = threadIdx.x; t < NBU_U; t += 256) hU[t] = 0;
  for (int t = threadIdx.x; t < NBU_I; t += 256) hI[t] = 0;
  __syncthreads();
  int base = blockIdx.x * CHUNK;
  int end = min(base + CHUNK, NE);
  for (int e = base + (threadIdx.x << 1); e < end; e += 512){
    int2 uu = *(const int2*)(u_idx + e);
    int2 ii = *(const int2*)(i_idx + e);
    atomicAdd(&hU[uu.x >> BSH], 1);
    atomicAdd(&hU[uu.y >> BSH], 1);
    atomicAdd(&hI[ii.x >> BSH], 1);
    atomicAdd(&hI[ii.y >> BSH], 1);
  }
  __syncthreads();
  for (int t = threadIdx.x; t < NBU_U; t += 256){
    int c = hU[t];
    baU[t] = c ? atomicAdd(&bcur_u[t], c) : 0;
    hU[t] = 0;
  }
  for (int t = threadIdx.x; t < NBU_I; t += 256){
    int c = hI[t];
    baI[t] = c ? atomicAdd(&bcur_i[t], c) : 0;
    hI[t] = 0;
  }
  __syncthreads();
  for (int e = base + (threadIdx.x << 1); e < end; e += 512){
    int2 uu = *(const int2*)(u_idx + e);
    int2 ii = *(const int2*)(i_idx + e);
    int bu0 = uu.x >> BSH, bu1 = uu.y >> BSH;
    int bi0 = ii.x >> BSH, bi1 = ii.y >> BSH;
    bin_u[baU[bu0] + atomicAdd(&hU[bu0], 1)] = ((uu.x & 127) << 24) | ii.x;
    bin_u[baU[bu1] + atomicAdd(&hU[bu1], 1)] = ((uu.y & 127) << 24) | ii.y;
    bin_i[baI[bi0] + atomicAdd(&hI[bi0], 1)] = ((ii.x & 127) << 24) | uu.x;
    bin_i[baI[bi1] + atomicAdd(&hI[bi1], 1)] = ((ii.y & 127) << 24) | uu.y;
  }
}

// ---------------- phase 2: per-bucket row counts (+ fused norms + degree hist) ----------------

__global__ void bucket_rowcnt_k(const int* __restrict__ bin, const int* __restrict__ boffs,
                                int* __restrict__ cnt, float* __restrict__ inv,
                                float* __restrict__ invs, int* __restrict__ dhist, int nrows){
  __shared__ int h[128];
  if (threadIdx.x < 128) h[threadIdx.x] = 0;
  __syncthreads();
  int b = blockIdx.x, r0 = b << BSH;
  int beg = boffs[b], end = boffs[b + 1];
  for (int e = beg + threadIdx.x; e < end; e += 256)
    atomicAdd(&h[((unsigned)bin[e]) >> 24], 1);
  __syncthreads();
  int row = r0 + threadIdx.x;
  if (threadIdx.x < 128 && row < nrows){
    int c = h[threadIdx.x];
    cnt[row] = c;
    float d = (c > 0) ? (float)c : 1.0f;
    inv[row]  = 1.0f / d;
    invs[row] = 1.0f / sqrtf(d);
    atomicAdd(&dhist[min(c, DBINS - 1)], 1);
  }
}

__global__ void bucket_fill_k(const int* __restrict__ bin, const int* __restrict__ boffs,
                              const int* __restrict__ offs, int* __restrict__ adj, int nrows){
  __shared__ int cur[128];
  int b = blockIdx.x, r0 = b << BSH;
  int row = r0 + threadIdx.x;
  if (threadIdx.x < 128) cur[threadIdx.x] = (row < nrows) ? offs[row] : 0;
  __syncthreads();
  int beg = boffs[b], end = boffs[b + 1];
  for (int e = beg + threadIdx.x; e < end; e += 256){
    int v = bin[e];
    int slot = atomicAdd(&cur[((unsigned)v) >> 24], 1);
    adj[slot] = v & 0xFFFFFF;
  }
}

// ---------------- row-offset scan (100K / 50K elements) ----------------

__global__ void scan1_k(const int* __restrict__ in, int* __restrict__ out,
                        int* __restrict__ partials, int n){
  __shared__ int sdata[256];
  int tid = threadIdx.x;
  int base = blockIdx.x * 2048 + tid * 8;
  int v[8]; int s = 0;
#pragma unroll
  for (int k = 0; k < 8; ++k){ int i = base + k; int x = (i < n) ? in[i] : 0; v[k] = s; s += x; }
  sdata[tid] = s; __syncthreads();
  for (int off = 1; off < 256; off <<= 1){
    int t = (tid >= off) ? sdata[tid - off] : 0;
    __syncthreads();
    sdata[tid] += t;
    __syncthreads();
  }
  int toff = (tid > 0) ? sdata[tid - 1] : 0;
  if (tid == 255) partials[blockIdx.x] = sdata[255];
#pragma unroll
  for (int k = 0; k < 8; ++k){ int i = base + k; if (i < n) out[i] = v[k] + toff; }
}

__global__ void scan2_k(int* partials, int nb){
  if (blockIdx.x == 0 && threadIdx.x == 0){
    int s = 0;
    for (int i = 0; i < nb; ++i){ int x = partials[i]; partials[i] = s; s += x; }
  }
}

__global__ void scan3_k(int* __restrict__ out, const int* __restrict__ partials,
                        int n, int total){
  int tid = threadIdx.x;
  int base = blockIdx.x * 2048 + tid * 8;
  int add = partials[blockIdx.x];
#pragma unroll
  for (int k = 0; k < 8; ++k){
    int i = base + k;
    if (i < n) out[i] += add;
  }
  if (blockIdx.x == 0 && tid == 0) out[n] = total;
}

// ---------------- degree sort (counting sort -> DESCENDING perm) ----------------

__global__ void deg_scatter_k(const int* __restrict__ cnt, int* __restrict__ dcur,
                              int* __restrict__ perm, int n){
  __shared__ int h[DBINS];
  __shared__ int base_s[DBINS];
  for (int t = threadIdx.x; t < DBINS; t += 256) h[t] = 0;
  __syncthreads();
  int base = blockIdx.x * 2048;
  int end = min(base + 2048, n);
  for (int r = base + threadIdx.x; r < end; r += 256)
    atomicAdd(&h[min(cnt[r], DBINS - 1)], 1);
  __syncthreads();
  for (int t = threadIdx.x; t < DBINS; t += 256){
    int c = h[t];
    base_s[t] = c ? atomicAdd(&dcur[t], c) : 0;
    h[t] = 0;
  }
  __syncthreads();
  for (int r = base + threadIdx.x; r < end; r += 256){
    int b = min(cnt[r], DBINS - 1);
    int pos = base_s[b] + atomicAdd(&h[b], 1);
    perm[n - 1 - pos] = r;   // descending degree: stragglers dispatch first
  }
}

// ---------------- fused init: out = 0.25*emb ; half tables = emb * pre-scale ----------------

__global__ void init_k(const float* __restrict__ ue, const float* __restrict__ ie,
                       const float* __restrict__ dus, const float* __restrict__ dis,
                       float* __restrict__ out, __half* __restrict__ ue_h,
                       __half* __restrict__ ie_h){
  int idx4 = blockIdx.x * blockDim.x + threadIdx.x;   // one float4 per thread
  const int nu4 = U_NUM * (EMB / 4);
  const int tot4 = (U_NUM + I_NUM) * (EMB / 4);
  if (idx4 >= tot4) return;
  const float* e; __half* hp; float s; int loc;
  if (idx4 < nu4){ e = ue; hp = ue_h; loc = idx4; s = dus[idx4 >> 4]; }
  else { e = ie; hp = ie_h; loc = idx4 - nu4; s = dis[(idx4 - nu4) >> 4]; }
  float4 v = ((const float4*)e)[loc];
  float4 o = make_float4(v.x * 0.25f, v.y * 0.25f, v.z * 0.25f, v.w * 0.25f);
  ((float4*)out)[idx4] = o;
  __half2 h01 = __floats2half2_rn(v.x * s, v.y * s);
  __half2 h23 = __floats2half2_rn(v.z * s, v.w * s);
  ((__half2*)hp)[loc * 2]     = h01;
  ((__half2*)hp)[loc * 2 + 1] = h23;
}

// ---------------- fp16 gather SpMM ----------------
// 4 lanes per row, each lane owns 16 halves (2x float4 load per edge, 128B/row).
// unroll x2 -> 4 loads (8 KB/wave) in flight. perm is degree-DESCENDING.
// Epilogue: dst_h[row] = half(acc * post_h[row]); if HAS_SUM:
//   sum[row] += acc * post_sum[row] * 0.25   (final averaging folded in)

__device__ __forceinline__ void acc8(float* a, float4 v){
  union { float4 f; __half2 h[4]; } u;
  u.f = v;
#pragma unroll
  for (int k = 0; k < 4; ++k){
    float2 f = __half22float2(u.h[k]);
    a[2*k]     += f.x;
    a[2*k + 1] += f.y;
  }
}

template<bool HAS_SUM>
__global__ void spmm_h(const int* __restrict__ offs, const int* __restrict__ adj,
                       const int* __restrict__ perm,
                       const __half* __restrict__ src,
                       const float* __restrict__ post_sum,
                       const float* __restrict__ post_h,
                       __half* __restrict__ dst_h,
                       float* __restrict__ sum, int nrows){
  int t = blockIdx.x * blockDim.x + threadIdx.x;
  int rid = t >> 2;
  if (rid >= nrows) return;
  int lane = t & 3;
  int row = perm[rid];
  int beg = offs[row], end = offs[row + 1];
  const size_t hoff = (size_t)(lane << 4);   // in halves: lane*16 (32 B)
  float acc[16];
#pragma unroll
  for (int k = 0; k < 16; ++k) acc[k] = 0.f;
  int j = beg;
  for (; j + 1 < end; j += 2){
    int n0 = adj[j], n1 = adj[j + 1];
    const float4* p0 = (const float4*)(src + (((size_t)n0) << 6) + hoff);
    const float4* p1 = (const float4*)(src + (((size_t)n1) << 6) + hoff);
    float4 a0 = p0[0];
    float4 a1 = p0[1];
    float4 b0 = p1[0];
    float4 b1 = p1[1];
    acc8(acc, a0); acc8(acc + 8, a1);
    acc8(acc, b0); acc8(acc + 8, b1);
  }
  if (j < end){
    int n0 = adj[j];
    const float4* p0 = (const float4*)(src + (((size_t)n0) << 6) + hoff);
    float4 a0 = p0[0];
    float4 a1 = p0[1];
    acc8(acc, a0); acc8(acc + 8, a1);
  }
  float ph = post_h[row];
  union { float4 f[2]; __half2 h[8]; } ob;
#pragma unroll
  for (int k = 0; k < 8; ++k)
    ob.h[k] = __floats2half2_rn(acc[2*k] * ph, acc[2*k + 1] * ph);
  float4* dp = (float4*)(dst_h + (((size_t)row) << 6) + hoff);
  dp[0] = ob.f[0];
  dp[1] = ob.f[1];
  if (HAS_SUM){
    float ps = post_sum[row] * 0.25f;
    float4* sp = (float4*)(sum + (((size_t)row) << 6) + (size_t)(lane << 4));
#pragma unroll
    for (int k = 0; k < 4; ++k){
      float4 s = sp[k];
      s.x += acc[4*k]     * ps;
      s.y += acc[4*k + 1] * ps;
      s.z += acc[4*k + 2] * ps;
      s.w += acc[4*k + 3] * ps;
      sp[k] = s;
    }
  }
}

// ---------------- driver ----------------

extern "C" void kernel_launch(void* const* d_in, const int* in_sizes, int n_in,
                              void* d_out, int out_size, void* d_ws, size_t ws_size,
                              hipStream_t stream){
  const float* user_emb = (const float*)d_in[0];
  const float* item_emb = (const float*)d_in[1];
  const int*   u_idx    = (const int*)d_in[2];
  const int*   i_idx    = (const int*)d_in[3];
  float* out = (float*)d_out;

  char* w = (char*)d_ws;
  size_t off = 0;
  auto alloc = [&](size_t bytes) -> void* {
    void* p = (void*)(w + off);
    off += (bytes + 255) & ~(size_t)255;
    return p;
  };
  int* cnt_u   = (int*)alloc((size_t)U_NUM * 4);
  int* cnt_i   = (int*)alloc((size_t)I_NUM * 4);
  int* offs_u  = (int*)alloc((size_t)(U_NUM + 1) * 4);
  int* offs_i  = (int*)alloc((size_t)(I_NUM + 1) * 4);
  int* part_u  = (int*)alloc(64 * 4);
  int* part_i  = (int*)alloc(64 * 4);
  int* bcnt_u  = (int*)alloc((size_t)NBU_U * 4);
  int* bcnt_i  = (int*)alloc((size_t)NBU_I * 4);
  int* boffs_u = (int*)alloc((size_t)(NBU_U + 1) * 4);
  int* boffs_i = (int*)alloc((size_t)(NBU_I + 1) * 4);
  int* bcur_u  = (int*)alloc((size_t)NBU_U * 4);
  int* bcur_i  = (int*)alloc((size_t)NBU_I * 4);
  int* dhist_u = (int*)alloc((size_t)DBINS * 4);
  int* dhist_i = (int*)alloc((size_t)DBINS * 4);
  int* doffs_u = (int*)alloc((size_t)(DBINS + 1) * 4);
  int* doffs_i = (int*)alloc((size_t)(DBINS + 1) * 4);
  int* dcur_u  = (int*)alloc((size_t)DBINS * 4);
  int* dcur_i  = (int*)alloc((size_t)DBINS * 4);
  int* perm_u  = (int*)alloc((size_t)U_NUM * 4);
  int* perm_i  = (int*)alloc((size_t)I_NUM * 4);
  int* adj_u   = (int*)alloc((size_t)NE * 4);
  int* adj_i   = (int*)alloc((size_t)NE * 4);
  float* du_inv  = (float*)alloc((size_t)U_NUM * 4);
  float* du_invs = (float*)alloc((size_t)U_NUM * 4);
  float* di_inv  = (float*)alloc((size_t)I_NUM * 4);
  float* di_invs = (float*)alloc((size_t)I_NUM * 4);
  // half-table region, 38.4 MB; the packed bins (16 MB) alias its start and
  // are dead before init_k writes the half tables.
  __half* hreg = (__half*)alloc((size_t)(U_NUM + I_NUM) * 2 * EMB * 2);
  __half* ue_h    = hreg;                                  // U_NUM*64
  __half* ie_h    = ue_h    + (size_t)U_NUM * EMB;         // I_NUM*64
  __half* tmp_i_h = ie_h    + (size_t)I_NUM * EMB;         // I_NUM*64
  __half* tmp_u_h = tmp_i_h + (size_t)I_NUM * EMB;         // U_NUM*64
  int* bin_u = (int*)hreg;            // NE ints (8 MB)
  int* bin_i = bin_u + NE;            // NE ints (8 MB)

  // ---- CSR build (binned, packed) ----
  hipMemsetAsync(bcnt_u, 0, (size_t)NBU_U * 4, stream);
  hipMemsetAsync(bcnt_i, 0, (size_t)NBU_I * 4, stream);
  hipMemsetAsync(dhist_u, 0, (size_t)DBINS * 4, stream);
  hipMemsetAsync(dhist_i, 0, (size_t)DBINS * 4, stream);

  bucket_hist_k<<<NBLK_E, 256, 0, stream>>>(u_idx, i_idx, bcnt_u, bcnt_i);
  small_scan_k<<<1, 1024, 0, stream>>>(bcnt_u, boffs_u, bcur_u, NBU_U);
  small_scan_k<<<1, 1024, 0, stream>>>(bcnt_i, boffs_i, bcur_i, NBU_I);
  binfill_k<<<NBLK_E, 256, 0, stream>>>(u_idx, i_idx, bcur_u, bcur_i, bin_u, bin_i);

  bucket_rowcnt_k<<<NBU_U, 256, 0, stream>>>(bin_u, boffs_u, cnt_u, du_inv, du_invs, dhist_u, U_NUM);
  bucket_rowcnt_k<<<NBU_I, 256, 0, stream>>>(bin_i, boffs_i, cnt_i, di_inv, di_invs, dhist_i, I_NUM);

  int nbu = ceil_div(U_NUM, 2048), nbi = ceil_div(I_NUM, 2048);
  scan1_k<<<nbu, 256, 0, stream>>>(cnt_u, offs_u, part_u, U_NUM);
  scan1_k<<<nbi, 256, 0, stream>>>(cnt_i, offs_i, part_i, I_NUM);
  scan2_k<<<1, 64, 0, stream>>>(part_u, nbu);
  scan2_k<<<1, 64, 0, stream>>>(part_i, nbi);
  scan3_k<<<nbu, 256, 0, stream>>>(offs_u, part_u, U_NUM, NE);
  scan3_k<<<nbi, 256, 0, stream>>>(offs_i, part_i, I_NUM, NE);

  bucket_fill_k<<<NBU_U, 256, 0, stream>>>(bin_u, boffs_u, offs_u, adj_u, U_NUM);
  bucket_fill_k<<<NBU_I, 256, 0, stream>>>(bin_i, boffs_i, offs_i, adj_i, I_NUM);

  // ---- degree sort (descending) ----
  small_scan_k<<<1, 1024, 0, stream>>>(dhist_u, doffs_u, dcur_u, DBINS);
  small_scan_k<<<1, 1024, 0, stream>>>(dhist_i, doffs_i, dcur_i, DBINS);
  deg_scatter_k<<<nbu, 256, 0, stream>>>(cnt_u, dcur_u, perm_u, U_NUM);
  deg_scatter_k<<<nbi, 256, 0, stream>>>(cnt_i, dcur_i, perm_i, I_NUM);

  // ---- propagation (fp16 tables, fp32 accumulation) ----
  init_k<<<ceil_div((U_NUM + I_NUM) * EMB / 4, 256), 256, 0, stream>>>(
      user_emb, item_emb, du_invs, di_invs, out, ue_h, ie_h);

  float* sum_u = out;
  float* sum_i = out + (size_t)U_NUM * EMB;
  for (int l = 0; l < NLAYERS; ++l){
    // A: tmp_i_h = half(d_i_inv * R^T ue_h)           (ue_h pre-scaled by du_invs)
    spmm_h<false><<<ceil_div(I_NUM * 4, 256), 256, 0, stream>>>(
        offs_i, adj_i, perm_i, ue_h, nullptr, di_inv, tmp_i_h, nullptr, I_NUM);
    // B: sum_u += 0.25 * du_invs * R tmp_i_h ; ue_h = half(du_inv * R tmp_i_h)
    spmm_h<true><<<ceil_div(U_NUM * 4, 256), 256, 0, stream>>>(
        offs_u, adj_u, perm_u, tmp_i_h, du_invs, du_inv, ue_h, sum_u, U_NUM);
    // C: tmp_u_h = half(d_u_inv * R ie_h)             (ie_h pre-scaled by di_invs)
    spmm_h<false><<<ceil_div(U_NUM * 4, 256), 256, 0, stream>>>(
        offs_u, adj_u, perm_u, ie_h, nullptr, du_inv, tmp_u_h, nullptr, U_NUM);
    // D: sum_i += 0.25 * di_invs * R^T tmp_u_h ; ie_h = half(di_inv * R^T tmp_u_h)
    spmm_h<true><<<ceil_div(I_NUM * 4, 256), 256, 0, stream>>>(
        offs_i, adj_i, perm_i, tmp_u_h, di_invs, di_inv, ie_h, sum_i, I_NUM);
  }
}

// Round 5
// 814.722 us; speedup vs baseline: 1.4635x; 1.4635x over previous
//
#include <hip/hip_runtime.h>
#include <hip/hip_fp16.h>
#include <math.h>

#define U_NUM 100000
#define I_NUM 50000
#define NE    2000000
#define EMB   64
#define NLAYERS 3

// bucketing: 128 rows per bucket
#define BSH   7
#define NBU_U ((U_NUM + 127) >> 7)   // 782
#define NBU_I ((I_NUM + 127) >> 7)   // 391
#define CHUNK 2048
#define NBLK_E ((NE + CHUNK - 1) / CHUNK)
#define DBINS 512

static inline int ceil_div(int a, int b){ return (a + b - 1) / b; }

// ---------------- phase 1: bucket partition ----------------

__global__ void bucket_hist_k(const int* __restrict__ u_idx, const int* __restrict__ i_idx,
                              int* __restrict__ bcnt_u, int* __restrict__ bcnt_i){
  __shared__ int hU[NBU_U];
  __shared__ int hI[NBU_I];
  for (int t = threadIdx.x; t < NBU_U; t += 256) hU[t] = 0;
  for (int t = threadIdx.x; t < NBU_I; t += 256) hI[t] = 0;
  __syncthreads();
  int base = blockIdx.x * CHUNK;
  int end = min(base + CHUNK, NE);
  // base/end always even (NE even, CHUNK even) -> int2 pairs safe
  for (int e = base + (threadIdx.x << 1); e < end; e += 512){
    int2 uu = *(const int2*)(u_idx + e);
    int2 ii = *(const int2*)(i_idx + e);
    atomicAdd(&hU[uu.x >> BSH], 1);
    atomicAdd(&hU[uu.y >> BSH], 1);
    atomicAdd(&hI[ii.x >> BSH], 1);
    atomicAdd(&hI[ii.y >> BSH], 1);
  }
  __syncthreads();
  for (int t = threadIdx.x; t < NBU_U; t += 256) if (hU[t]) atomicAdd(&bcnt_u[t], hU[t]);
  for (int t = threadIdx.x; t < NBU_I; t += 256) if (hI[t]) atomicAdd(&bcnt_i[t], hI[t]);
}

// single-block exclusive scan, n <= 1024; writes offs[0..n] and cur=offs
__global__ void small_scan_k(const int* __restrict__ cnt, int* __restrict__ offs,
                             int* __restrict__ cur, int n){
  __shared__ int s[1024];
  int t = threadIdx.x;
  int v = (t < n) ? cnt[t] : 0;
  s[t] = v; __syncthreads();
  for (int o = 1; o < 1024; o <<= 1){
    int x = (t >= o) ? s[t - o] : 0;
    __syncthreads();
    s[t] += x;
    __syncthreads();
  }
  int excl = (t > 0) ? s[t - 1] : 0;
  if (t < n){ offs[t] = excl; cur[t] = excl; }
  if (t == n - 1) offs[n] = s[t];
}

// packed bin entry: (row_local << 24) | neighbor   (row_local < 128, neighbor < 2^17)
__global__ void binfill_k(const int* __restrict__ u_idx, const int* __restrict__ i_idx,
                          int* __restrict__ bcur_u, int* __restrict__ bcur_i,
                          int* __restrict__ bin_u, int* __restrict__ bin_i){
  __shared__ int hU[NBU_U];
  __shared__ int hI[NBU_I];
  __shared__ int baU[NBU_U];
  __shared__ int baI[NBU_I];
  for (int t = threadIdx.x; t < NBU_U; t += 256) hU[t] = 0;
  for (int t = threadIdx.x; t < NBU_I; t += 256) hI[t] = 0;
  __syncthreads();
  int base = blockIdx.x * CHUNK;
  int end = min(base + CHUNK, NE);
  for (int e = base + (threadIdx.x << 1); e < end; e += 512){
    int2 uu = *(const int2*)(u_idx + e);
    int2 ii = *(const int2*)(i_idx + e);
    atomicAdd(&hU[uu.x >> BSH], 1);
    atomicAdd(&hU[uu.y >> BSH], 1);
    atomicAdd(&hI[ii.x >> BSH], 1);
    atomicAdd(&hI[ii.y >> BSH], 1);
  }
  __syncthreads();
  for (int t = threadIdx.x; t < NBU_U; t += 256){
    int c = hU[t];
    baU[t] = c ? atomicAdd(&bcur_u[t], c) : 0;
    hU[t] = 0;
  }
  for (int t = threadIdx.x; t < NBU_I; t += 256){
    int c = hI[t];
    baI[t] = c ? atomicAdd(&bcur_i[t], c) : 0;
    hI[t] = 0;
  }
  __syncthreads();
  for (int e = base + (threadIdx.x << 1); e < end; e += 512){
    int2 uu = *(const int2*)(u_idx + e);
    int2 ii = *(const int2*)(i_idx + e);
    int bu0 = uu.x >> BSH, bu1 = uu.y >> BSH;
    int bi0 = ii.x >> BSH, bi1 = ii.y >> BSH;
    bin_u[baU[bu0] + atomicAdd(&hU[bu0], 1)] = ((uu.x & 127) << 24) | ii.x;
    bin_u[baU[bu1] + atomicAdd(&hU[bu1], 1)] = ((uu.y & 127) << 24) | ii.y;
    bin_i[baI[bi0] + atomicAdd(&hI[bi0], 1)] = ((ii.x & 127) << 24) | uu.x;
    bin_i[baI[bi1] + atomicAdd(&hI[bi1], 1)] = ((ii.y & 127) << 24) | uu.y;
  }
}

// ---------------- phase 2: per-bucket row counts (+ fused norms, NO global hist) ----------------

__global__ void bucket_rowcnt_k(const int* __restrict__ bin, const int* __restrict__ boffs,
                                int* __restrict__ cnt, float* __restrict__ inv,
                                float* __restrict__ invs, int nrows){
  __shared__ int h[128];
  if (threadIdx.x < 128) h[threadIdx.x] = 0;
  __syncthreads();
  int b = blockIdx.x, r0 = b << BSH;
  int beg = boffs[b], end = boffs[b + 1];
  for (int e = beg + threadIdx.x; e < end; e += 256)
    atomicAdd(&h[((unsigned)bin[e]) >> 24], 1);
  __syncthreads();
  int row = r0 + threadIdx.x;
  if (threadIdx.x < 128 && row < nrows){
    int c = h[threadIdx.x];
    cnt[row] = c;
    float d = (c > 0) ? (float)c : 1.0f;
    inv[row]  = 1.0f / d;
    invs[row] = 1.0f / sqrtf(d);
  }
}

__global__ void bucket_fill_k(const int* __restrict__ bin, const int* __restrict__ boffs,
                              const int* __restrict__ offs, int* __restrict__ adj, int nrows){
  __shared__ int cur[128];
  int b = blockIdx.x, r0 = b << BSH;
  int row = r0 + threadIdx.x;
  if (threadIdx.x < 128) cur[threadIdx.x] = (row < nrows) ? offs[row] : 0;
  __syncthreads();
  int beg = boffs[b], end = boffs[b + 1];
  for (int e = beg + threadIdx.x; e < end; e += 256){
    int v = bin[e];
    int slot = atomicAdd(&cur[((unsigned)v) >> 24], 1);
    adj[slot] = v & 0xFFFFFF;
  }
}

// ---------------- row-offset scan (100K / 50K elements) ----------------

__global__ void scan1_k(const int* __restrict__ in, int* __restrict__ out,
                        int* __restrict__ partials, int n){
  __shared__ int sdata[256];
  int tid = threadIdx.x;
  int base = blockIdx.x * 2048 + tid * 8;
  int v[8]; int s = 0;
#pragma unroll
  for (int k = 0; k < 8; ++k){ int i = base + k; int x = (i < n) ? in[i] : 0; v[k] = s; s += x; }
  sdata[tid] = s; __syncthreads();
  for (int off = 1; off < 256; off <<= 1){
    int t = (tid >= off) ? sdata[tid - off] : 0;
    __syncthreads();
    sdata[tid] += t;
    __syncthreads();
  }
  int toff = (tid > 0) ? sdata[tid - 1] : 0;
  if (tid == 255) partials[blockIdx.x] = sdata[255];
#pragma unroll
  for (int k = 0; k < 8; ++k){ int i = base + k; if (i < n) out[i] = v[k] + toff; }
}

__global__ void scan2_k(int* partials, int nb){
  if (blockIdx.x == 0 && threadIdx.x == 0){
    int s = 0;
    for (int i = 0; i < nb; ++i){ int x = partials[i]; partials[i] = s; s += x; }
  }
}

__global__ void scan3_k(int* __restrict__ out, const int* __restrict__ partials,
                        int n, int total){
  int tid = threadIdx.x;
  int base = blockIdx.x * 2048 + tid * 8;
  int add = partials[blockIdx.x];
#pragma unroll
  for (int k = 0; k < 8; ++k){
    int i = base + k;
    if (i < n) out[i] += add;
  }
  if (blockIdx.x == 0 && tid == 0) out[n] = total;
}

// ---------------- degree sort (LDS-staged hist; counting sort -> DESCENDING perm) ----------------

__global__ void deg_hist_k(const int* __restrict__ cnt, int* __restrict__ dhist, int n){
  __shared__ int h[DBINS];
  for (int t = threadIdx.x; t < DBINS; t += 256) h[t] = 0;
  __syncthreads();
  int base = blockIdx.x * 2048;
  int end = min(base + 2048, n);
  for (int r = base + threadIdx.x; r < end; r += 256)
    atomicAdd(&h[min(cnt[r], DBINS - 1)], 1);
  __syncthreads();
  for (int t = threadIdx.x; t < DBINS; t += 256) if (h[t]) atomicAdd(&dhist[t], h[t]);
}

__global__ void deg_scatter_k(const int* __restrict__ cnt, int* __restrict__ dcur,
                              int* __restrict__ perm, int n){
  __shared__ int h[DBINS];
  __shared__ int base_s[DBINS];
  for (int t = threadIdx.x; t < DBINS; t += 256) h[t] = 0;
  __syncthreads();
  int base = blockIdx.x * 2048;
  int end = min(base + 2048, n);
  for (int r = base + threadIdx.x; r < end; r += 256)
    atomicAdd(&h[min(cnt[r], DBINS - 1)], 1);
  __syncthreads();
  for (int t = threadIdx.x; t < DBINS; t += 256){
    int c = h[t];
    base_s[t] = c ? atomicAdd(&dcur[t], c) : 0;
    h[t] = 0;
  }
  __syncthreads();
  for (int r = base + threadIdx.x; r < end; r += 256){
    int b = min(cnt[r], DBINS - 1);
    int pos = base_s[b] + atomicAdd(&h[b], 1);
    perm[n - 1 - pos] = r;   // descending degree: stragglers dispatch first
  }
}

// ---------------- fused init: out = 0.25*emb ; half tables = emb * pre-scale ----------------

__global__ void init_k(const float* __restrict__ ue, const float* __restrict__ ie,
                       const float* __restrict__ dus, const float* __restrict__ dis,
                       float* __restrict__ out, __half* __restrict__ ue_h,
                       __half* __restrict__ ie_h){
  int idx4 = blockIdx.x * blockDim.x + threadIdx.x;   // one float4 per thread
  const int nu4 = U_NUM * (EMB / 4);
  const int tot4 = (U_NUM + I_NUM) * (EMB / 4);
  if (idx4 >= tot4) return;
  const float* e; __half* hp; float s; int loc;
  if (idx4 < nu4){ e = ue; hp = ue_h; loc = idx4; s = dus[idx4 >> 4]; }
  else { e = ie; hp = ie_h; loc = idx4 - nu4; s = dis[(idx4 - nu4) >> 4]; }
  float4 v = ((const float4*)e)[loc];
  float4 o = make_float4(v.x * 0.25f, v.y * 0.25f, v.z * 0.25f, v.w * 0.25f);
  ((float4*)out)[idx4] = o;
  __half2 h01 = __floats2half2_rn(v.x * s, v.y * s);
  __half2 h23 = __floats2half2_rn(v.z * s, v.w * s);
  ((__half2*)hp)[loc * 2]     = h01;
  ((__half2*)hp)[loc * 2 + 1] = h23;
}

// ---------------- fp16 gather SpMM ----------------
// 4 lanes per row, each lane owns 16 halves (2x float4 load per edge, 128B/row).
// unroll x2 -> 4 loads (8 KB/wave) in flight. perm is degree-DESCENDING.
// Epilogue: dst_h[row] = half(acc * post_h[row]); if HAS_SUM:
//   sum[row] += acc * post_sum[row] * 0.25   (final averaging folded in)

__device__ __forceinline__ void acc8(float* a, float4 v){
  union { float4 f; __half2 h[4]; } u;
  u.f = v;
#pragma unroll
  for (int k = 0; k < 4; ++k){
    float2 f = __half22float2(u.h[k]);
    a[2*k]     += f.x;
    a[2*k + 1] += f.y;
  }
}

template<bool HAS_SUM>
__global__ void spmm_h(const int* __restrict__ offs, const int* __restrict__ adj,
                       const int* __restrict__ perm,
                       const __half* __restrict__ src,
                       const float* __restrict__ post_sum,
                       const float* __restrict__ post_h,
                       __half* __restrict__ dst_h,
                       float* __restrict__ sum, int nrows){
  int t = blockIdx.x * blockDim.x + threadIdx.x;
  int rid = t >> 2;
  if (rid >= nrows) return;
  int lane = t & 3;
  int row = perm[rid];
  int beg = offs[row], end = offs[row + 1];
  const size_t hoff = (size_t)(lane << 4);   // in halves: lane*16 (32 B)
  float acc[16];
#pragma unroll
  for (int k = 0; k < 16; ++k) acc[k] = 0.f;
  int j = beg;
  for (; j + 1 < end; j += 2){
    int n0 = adj[j], n1 = adj[j + 1];
    const float4* p0 = (const float4*)(src + (((size_t)n0) << 6) + hoff);
    const float4* p1 = (const float4*)(src + (((size_t)n1) << 6) + hoff);
    float4 a0 = p0[0];
    float4 a1 = p0[1];
    float4 b0 = p1[0];
    float4 b1 = p1[1];
    acc8(acc, a0); acc8(acc + 8, a1);
    acc8(acc, b0); acc8(acc + 8, b1);
  }
  if (j < end){
    int n0 = adj[j];
    const float4* p0 = (const float4*)(src + (((size_t)n0) << 6) + hoff);
    float4 a0 = p0[0];
    float4 a1 = p0[1];
    acc8(acc, a0); acc8(acc + 8, a1);
  }
  float ph = post_h[row];
  union { float4 f[2]; __half2 h[8]; } ob;
#pragma unroll
  for (int k = 0; k < 8; ++k)
    ob.h[k] = __floats2half2_rn(acc[2*k] * ph, acc[2*k + 1] * ph);
  float4* dp = (float4*)(dst_h + (((size_t)row) << 6) + hoff);
  dp[0] = ob.f[0];
  dp[1] = ob.f[1];
  if (HAS_SUM){
    float ps = post_sum[row] * 0.25f;
    float4* sp = (float4*)(sum + (((size_t)row) << 6) + (size_t)(lane << 4));
#pragma unroll
    for (int k = 0; k < 4; ++k){
      float4 s = sp[k];
      s.x += acc[4*k]     * ps;
      s.y += acc[4*k + 1] * ps;
      s.z += acc[4*k + 2] * ps;
      s.w += acc[4*k + 3] * ps;
      sp[k] = s;
    }
  }
}

// ---------------- driver ----------------

extern "C" void kernel_launch(void* const* d_in, const int* in_sizes, int n_in,
                              void* d_out, int out_size, void* d_ws, size_t ws_size,
                              hipStream_t stream){
  const float* user_emb = (const float*)d_in[0];
  const float* item_emb = (const float*)d_in[1];
  const int*   u_idx    = (const int*)d_in[2];
  const int*   i_idx    = (const int*)d_in[3];
  float* out = (float*)d_out;

  char* w = (char*)d_ws;
  size_t off = 0;
  auto alloc = [&](size_t bytes) -> void* {
    void* p = (void*)(w + off);
    off += (bytes + 255) & ~(size_t)255;
    return p;
  };
  int* cnt_u   = (int*)alloc((size_t)U_NUM * 4);
  int* cnt_i   = (int*)alloc((size_t)I_NUM * 4);
  int* offs_u  = (int*)alloc((size_t)(U_NUM + 1) * 4);
  int* offs_i  = (int*)alloc((size_t)(I_NUM + 1) * 4);
  int* part_u  = (int*)alloc(64 * 4);
  int* part_i  = (int*)alloc(64 * 4);
  int* bcnt_u  = (int*)alloc((size_t)NBU_U * 4);
  int* bcnt_i  = (int*)alloc((size_t)NBU_I * 4);
  int* boffs_u = (int*)alloc((size_t)(NBU_U + 1) * 4);
  int* boffs_i = (int*)alloc((size_t)(NBU_I + 1) * 4);
  int* bcur_u  = (int*)alloc((size_t)NBU_U * 4);
  int* bcur_i  = (int*)alloc((size_t)NBU_I * 4);
  int* dhist_u = (int*)alloc((size_t)DBINS * 4);
  int* dhist_i = (int*)alloc((size_t)DBINS * 4);
  int* doffs_u = (int*)alloc((size_t)(DBINS + 1) * 4);
  int* doffs_i = (int*)alloc((size_t)(DBINS + 1) * 4);
  int* dcur_u  = (int*)alloc((size_t)DBINS * 4);
  int* dcur_i  = (int*)alloc((size_t)DBINS * 4);
  int* perm_u  = (int*)alloc((size_t)U_NUM * 4);
  int* perm_i  = (int*)alloc((size_t)I_NUM * 4);
  int* adj_u   = (int*)alloc((size_t)NE * 4);
  int* adj_i   = (int*)alloc((size_t)NE * 4);
  float* du_inv  = (float*)alloc((size_t)U_NUM * 4);
  float* du_invs = (float*)alloc((size_t)U_NUM * 4);
  float* di_inv  = (float*)alloc((size_t)I_NUM * 4);
  float* di_invs = (float*)alloc((size_t)I_NUM * 4);
  // half-table region, 38.4 MB; the packed bins (16 MB) alias its start and
  // are dead before init_k writes the half tables.
  __half* hreg = (__half*)alloc((size_t)(U_NUM + I_NUM) * 2 * EMB * 2);
  __half* ue_h    = hreg;                                  // U_NUM*64
  __half* ie_h    = ue_h    + (size_t)U_NUM * EMB;         // I_NUM*64
  __half* tmp_i_h = ie_h    + (size_t)I_NUM * EMB;         // I_NUM*64
  __half* tmp_u_h = tmp_i_h + (size_t)I_NUM * EMB;         // U_NUM*64
  int* bin_u = (int*)hreg;            // NE ints (8 MB)
  int* bin_i = bin_u + NE;            // NE ints (8 MB)

  // ---- CSR build (binned, packed) ----
  hipMemsetAsync(bcnt_u, 0, (size_t)NBU_U * 4, stream);
  hipMemsetAsync(bcnt_i, 0, (size_t)NBU_I * 4, stream);
  hipMemsetAsync(dhist_u, 0, (size_t)DBINS * 4, stream);
  hipMemsetAsync(dhist_i, 0, (size_t)DBINS * 4, stream);

  bucket_hist_k<<<NBLK_E, 256, 0, stream>>>(u_idx, i_idx, bcnt_u, bcnt_i);
  small_scan_k<<<1, 1024, 0, stream>>>(bcnt_u, boffs_u, bcur_u, NBU_U);
  small_scan_k<<<1, 1024, 0, stream>>>(bcnt_i, boffs_i, bcur_i, NBU_I);
  binfill_k<<<NBLK_E, 256, 0, stream>>>(u_idx, i_idx, bcur_u, bcur_i, bin_u, bin_i);

  bucket_rowcnt_k<<<NBU_U, 256, 0, stream>>>(bin_u, boffs_u, cnt_u, du_inv, du_invs, U_NUM);
  bucket_rowcnt_k<<<NBU_I, 256, 0, stream>>>(bin_i, boffs_i, cnt_i, di_inv, di_invs, I_NUM);

  int nbu = ceil_div(U_NUM, 2048), nbi = ceil_div(I_NUM, 2048);
  scan1_k<<<nbu, 256, 0, stream>>>(cnt_u, offs_u, part_u, U_NUM);
  scan1_k<<<nbi, 256, 0, stream>>>(cnt_i, offs_i, part_i, I_NUM);
  scan2_k<<<1, 64, 0, stream>>>(part_u, nbu);
  scan2_k<<<1, 64, 0, stream>>>(part_i, nbi);
  scan3_k<<<nbu, 256, 0, stream>>>(offs_u, part_u, U_NUM, NE);
  scan3_k<<<nbi, 256, 0, stream>>>(offs_i, part_i, I_NUM, NE);

  bucket_fill_k<<<NBU_U, 256, 0, stream>>>(bin_u, boffs_u, offs_u, adj_u, U_NUM);
  bucket_fill_k<<<NBU_I, 256, 0, stream>>>(bin_i, boffs_i, offs_i, adj_i, I_NUM);

  // ---- degree sort (LDS-staged hist, descending perm) ----
  deg_hist_k<<<nbu, 256, 0, stream>>>(cnt_u, dhist_u, U_NUM);
  deg_hist_k<<<nbi, 256, 0, stream>>>(cnt_i, dhist_i, I_NUM);
  small_scan_k<<<1, 1024, 0, stream>>>(dhist_u, doffs_u, dcur_u, DBINS);
  small_scan_k<<<1, 1024, 0, stream>>>(dhist_i, doffs_i, dcur_i, DBINS);
  deg_scatter_k<<<nbu, 256, 0, stream>>>(cnt_u, dcur_u, perm_u, U_NUM);
  deg_scatter_k<<<nbi, 256, 0, stream>>>(cnt_i, dcur_i, perm_i, I_NUM);

  // ---- propagation (fp16 tables, fp32 accumulation) ----
  init_k<<<ceil_div((U_NUM + I_NUM) * EMB / 4, 256), 256, 0, stream>>>(
      user_emb, item_emb, du_invs, di_invs, out, ue_h, ie_h);

  float* sum_u = out;
  float* sum_i = out + (size_t)U_NUM * EMB;
  for (int l = 0; l < NLAYERS; ++l){
    // A: tmp_i_h = half(d_i_inv * R^T ue_h)           (ue_h pre-scaled by du_invs)
    spmm_h<false><<<ceil_div(I_NUM * 4, 256), 256, 0, stream>>>(
        offs_i, adj_i, perm_i, ue_h, nullptr, di_inv, tmp_i_h, nullptr, I_NUM);
    // B: sum_u += 0.25 * du_invs * R tmp_i_h ; ue_h = half(du_inv * R tmp_i_h)
    spmm_h<true><<<ceil_div(U_NUM * 4, 256), 256, 0, stream>>>(
        offs_u, adj_u, perm_u, tmp_i_h, du_invs, du_inv, ue_h, sum_u, U_NUM);
    // C: tmp_u_h = half(d_u_inv * R ie_h)             (ie_h pre-scaled by di_invs)
    spmm_h<false><<<ceil_div(U_NUM * 4, 256), 256, 0, stream>>>(
        offs_u, adj_u, perm_u, ie_h, nullptr, du_inv, tmp_u_h, nullptr, U_NUM);
    // D: sum_i += 0.25 * di_invs * R^T tmp_u_h ; ie_h = half(di_inv * R^T tmp_u_h)
    spmm_h<true><<<ceil_div(I_NUM * 4, 256), 256, 0, stream>>>(
        offs_i, adj_i, perm_i, tmp_u_h, di_invs, di_inv, ie_h, sum_i, I_NUM);
  }
}

// Round 6
// 667.948 us; speedup vs baseline: 1.7851x; 1.2197x over previous
//
#include <hip/hip_runtime.h>
#include <hip/hip_fp16.h>
#include <math.h>

#define U_NUM 100000
#define I_NUM 50000
#define NE    2000000
#define EMB   64
#define NLAYERS 3

// bucketing: 512 rows per bucket
#define BSH   9
#define BROWS 512
#define NBU_U ((U_NUM + 511) >> 9)   // 196
#define NBU_I ((I_NUM + 511) >> 9)   // 98
#define NBU_T (NBU_U + NBU_I)        // 294
#define CHUNK 8192
#define NBLK_E ((NE + CHUNK - 1) / CHUNK)   // 245  (must stay <= 256 for colscan_k)
#define DBINS 512
#define PACK_SH 17
#define PACK_MASK 0x1FFFF

static inline int ceil_div(int a, int b){ return (a + b - 1) / b; }

// ---------------- phase 1: per-block bucket counts ----------------

__global__ void hist_k(const int* __restrict__ u_idx, const int* __restrict__ i_idx,
                       int* __restrict__ cm_u, int* __restrict__ cm_i){
  __shared__ int h[NBU_T];
  for (int t = threadIdx.x; t < NBU_T; t += 256) h[t] = 0;
  __syncthreads();
  int base = blockIdx.x * CHUNK;
  int end = min(base + CHUNK, NE);
  for (int e = base + (threadIdx.x << 1); e < end; e += 512){
    int2 uu = *(const int2*)(u_idx + e);
    int2 ii = *(const int2*)(i_idx + e);
    atomicAdd(&h[uu.x >> BSH], 1);
    atomicAdd(&h[uu.y >> BSH], 1);
    atomicAdd(&h[NBU_U + (ii.x >> BSH)], 1);
    atomicAdd(&h[NBU_U + (ii.y >> BSH)], 1);
  }
  __syncthreads();
  for (int t = threadIdx.x; t < NBU_U; t += 256) cm_u[blockIdx.x * NBU_U + t] = h[t];
  for (int t = threadIdx.x; t < NBU_I; t += 256) cm_i[blockIdx.x * NBU_I + t] = h[NBU_U + t];
}

// column sums of the count matrices -> per-bucket totals
__global__ void colsum_k(const int* __restrict__ cm_u, const int* __restrict__ cm_i,
                         int* __restrict__ tot_u, int* __restrict__ tot_i){
  __shared__ int s[256];
  int j = blockIdx.x;
  const int* cm; int* tot; int jj, stride;
  if (j < NBU_U){ cm = cm_u; tot = tot_u; jj = j; stride = NBU_U; }
  else { cm = cm_i; tot = tot_i; jj = j - NBU_U; stride = NBU_I; }
  int acc = 0;
  for (int b = threadIdx.x; b < NBLK_E; b += 256) acc += cm[b * stride + jj];
  s[threadIdx.x] = acc; __syncthreads();
  for (int o = 128; o > 0; o >>= 1){
    if (threadIdx.x < o) s[threadIdx.x] += s[threadIdx.x + o];
    __syncthreads();
  }
  if (threadIdx.x == 0) tot[jj] = s[0];
}

// single-block exclusive scan, n <= 1024; writes offs[0..n] and cur=offs
__global__ void small_scan_k(const int* __restrict__ cnt, int* __restrict__ offs,
                             int* __restrict__ cur, int n){
  __shared__ int s[1024];
  int t = threadIdx.x;
  int v = (t < n) ? cnt[t] : 0;
  s[t] = v; __syncthreads();
  for (int o = 1; o < 1024; o <<= 1){
    int x = (t >= o) ? s[t - o] : 0;
    __syncthreads();
    s[t] += x;
    __syncthreads();
  }
  int excl = (t > 0) ? s[t - 1] : 0;
  if (t < n){ offs[t] = excl; cur[t] = excl; }
  if (t == n - 1) offs[n] = s[t];
}

// per-bucket column scan: basemat[b][j] = boffs[j] + sum_{b'<b} cm[b'][j]
__global__ void colscan_k(const int* __restrict__ cm_u, const int* __restrict__ cm_i,
                          const int* __restrict__ boffs_u, const int* __restrict__ boffs_i,
                          int* __restrict__ bm_u, int* __restrict__ bm_i){
  __shared__ int s[256];
  int j = blockIdx.x;
  const int* cm; const int* boffs; int* bm; int jj, stride;
  if (j < NBU_U){ cm = cm_u; boffs = boffs_u; bm = bm_u; jj = j; stride = NBU_U; }
  else { cm = cm_i; boffs = boffs_i; bm = bm_i; jj = j - NBU_U; stride = NBU_I; }
  int t = threadIdx.x;
  int v = (t < NBLK_E) ? cm[t * stride + jj] : 0;
  s[t] = v; __syncthreads();
  for (int o = 1; o < 256; o <<= 1){
    int x = (t >= o) ? s[t - o] : 0;
    __syncthreads();
    s[t] += x;
    __syncthreads();
  }
  int excl = (t > 0) ? s[t - 1] : 0;
  if (t < NBLK_E) bm[t * stride + jj] = excl + boffs[jj];
}

// ---------------- phase 2: scatter edges into bucket-sorted bins ----------------
// packed bin entry: (row_local << 17) | neighbor  (row_local < 512, neighbor < 2^17)

__global__ void binfill_k(const int* __restrict__ u_idx, const int* __restrict__ i_idx,
                          const int* __restrict__ bm_u, const int* __restrict__ bm_i,
                          int* __restrict__ bin_u, int* __restrict__ bin_i){
  __shared__ int cur[NBU_T];
  for (int t = threadIdx.x; t < NBU_U; t += 256) cur[t] = bm_u[blockIdx.x * NBU_U + t];
  for (int t = threadIdx.x; t < NBU_I; t += 256) cur[NBU_U + t] = bm_i[blockIdx.x * NBU_I + t];
  __syncthreads();
  int base = blockIdx.x * CHUNK;
  int end = min(base + CHUNK, NE);
  for (int e = base + (threadIdx.x << 1); e < end; e += 512){
    int2 uu = *(const int2*)(u_idx + e);
    int2 ii = *(const int2*)(i_idx + e);
    int p;
    p = atomicAdd(&cur[uu.x >> BSH], 1);            bin_u[p] = ((uu.x & 511) << PACK_SH) | ii.x;
    p = atomicAdd(&cur[uu.y >> BSH], 1);            bin_u[p] = ((uu.y & 511) << PACK_SH) | ii.y;
    p = atomicAdd(&cur[NBU_U + (ii.x >> BSH)], 1);  bin_i[p] = ((ii.x & 511) << PACK_SH) | uu.x;
    p = atomicAdd(&cur[NBU_U + (ii.y >> BSH)], 1);  bin_i[p] = ((ii.y & 511) << PACK_SH) | uu.y;
  }
}

// ---------------- phase 3: per-bucket CSR build (cnt/offs/norms/adj + LDS deg hist) ----------------

__global__ void bucket_build_k(const int* __restrict__ bin_u, const int* __restrict__ bin_i,
                               const int* __restrict__ boffs_u, const int* __restrict__ boffs_i,
                               int* __restrict__ cnt_u, int* __restrict__ cnt_i,
                               int* __restrict__ offs_u, int* __restrict__ offs_i,
                               float* __restrict__ du_inv, float* __restrict__ du_invs,
                               float* __restrict__ di_inv, float* __restrict__ di_invs,
                               int* __restrict__ adj_u, int* __restrict__ adj_i,
                               int* __restrict__ dhist_u, int* __restrict__ dhist_i){
  __shared__ int h[BROWS];
  __shared__ int part[256];
  __shared__ int dh[DBINS];
  int b = blockIdx.x;
  const int* bin; const int* boffs; int* cnt; int* offs; float* inv; float* invs;
  int* adj; int* dhist; int jj, nrows;
  if (b < NBU_U){
    bin = bin_u; boffs = boffs_u; cnt = cnt_u; offs = offs_u;
    inv = du_inv; invs = du_invs; adj = adj_u; dhist = dhist_u; jj = b; nrows = U_NUM;
  } else {
    bin = bin_i; boffs = boffs_i; cnt = cnt_i; offs = offs_i;
    inv = di_inv; invs = di_invs; adj = adj_i; dhist = dhist_i; jj = b - NBU_U; nrows = I_NUM;
  }
  int tid = threadIdx.x;
  int r0 = jj << BSH;
  int beg = boffs[jj], end = boffs[jj + 1];
  h[2*tid] = 0; h[2*tid + 1] = 0;
  for (int t = tid; t < DBINS; t += 256) dh[t] = 0;
  __syncthreads();
  for (int e = beg + tid; e < end; e += 256)
    atomicAdd(&h[((unsigned)bin[e]) >> PACK_SH], 1);
  __syncthreads();
  int c0 = h[2*tid], c1 = h[2*tid + 1];
  part[tid] = c0 + c1; __syncthreads();
  for (int o = 1; o < 256; o <<= 1){
    int x = (tid >= o) ? part[tid - o] : 0;
    __syncthreads();
    part[tid] += x;
    __syncthreads();
  }
  int excl = (tid > 0) ? part[tid - 1] : 0;
  h[2*tid] = excl;
  h[2*tid + 1] = excl + c0;
#pragma unroll
  for (int k = 0; k < 2; ++k){
    int l = 2*tid + k;
    int row = r0 + l;
    int c = k ? c1 : c0;
    int o = k ? (excl + c0) : excl;
    if (row < nrows){
      cnt[row] = c;
      offs[row] = beg + o;
      float d = (c > 0) ? (float)c : 1.0f;
      inv[row]  = 1.0f / d;
      invs[row] = 1.0f / sqrtf(d);
      atomicAdd(&dh[min(c, DBINS - 1)], 1);
    } else if (row == nrows){
      offs[row] = beg + o;   // global sentinel (== NE in the last bucket)
    }
  }
  __syncthreads();
  // scatter adj using h as cursors (bucket-local CSR layout)
  for (int e = beg + tid; e < end; e += 256){
    int v = bin[e];
    int slot = beg + atomicAdd(&h[((unsigned)v) >> PACK_SH], 1);
    adj[slot] = v & PACK_MASK;
  }
  __syncthreads();
  for (int t = tid; t < DBINS; t += 256) if (dh[t]) atomicAdd(&dhist[t], dh[t]);
}

// ---------------- degree sort (counting sort -> DESCENDING perm) ----------------

__global__ void deg_scatter_k(const int* __restrict__ cnt, int* __restrict__ dcur,
                              int* __restrict__ perm, int n){
  __shared__ int h[DBINS];
  __shared__ int base_s[DBINS];
  for (int t = threadIdx.x; t < DBINS; t += 256) h[t] = 0;
  __syncthreads();
  int base = blockIdx.x * 2048;
  int end = min(base + 2048, n);
  for (int r = base + threadIdx.x; r < end; r += 256)
    atomicAdd(&h[min(cnt[r], DBINS - 1)], 1);
  __syncthreads();
  for (int t = threadIdx.x; t < DBINS; t += 256){
    int c = h[t];
    base_s[t] = c ? atomicAdd(&dcur[t], c) : 0;
    h[t] = 0;
  }
  __syncthreads();
  for (int r = base + threadIdx.x; r < end; r += 256){
    int b = min(cnt[r], DBINS - 1);
    int pos = base_s[b] + atomicAdd(&h[b], 1);
    perm[n - 1 - pos] = r;   // descending degree: stragglers dispatch first
  }
}

// ---------------- fused init: out = 0.25*emb ; half tables = emb * pre-scale ----------------

__global__ void init_k(const float* __restrict__ ue, const float* __restrict__ ie,
                       const float* __restrict__ dus, const float* __restrict__ dis,
                       float* __restrict__ out, __half* __restrict__ ue_h,
                       __half* __restrict__ ie_h){
  int idx4 = blockIdx.x * blockDim.x + threadIdx.x;   // one float4 per thread
  const int nu4 = U_NUM * (EMB / 4);
  const int tot4 = (U_NUM + I_NUM) * (EMB / 4);
  if (idx4 >= tot4) return;
  const float* e; __half* hp; float s; int loc;
  if (idx4 < nu4){ e = ue; hp = ue_h; loc = idx4; s = dus[idx4 >> 4]; }
  else { e = ie; hp = ie_h; loc = idx4 - nu4; s = dis[(idx4 - nu4) >> 4]; }
  float4 v = ((const float4*)e)[loc];
  float4 o = make_float4(v.x * 0.25f, v.y * 0.25f, v.z * 0.25f, v.w * 0.25f);
  ((float4*)out)[idx4] = o;
  __half2 h01 = __floats2half2_rn(v.x * s, v.y * s);
  __half2 h23 = __floats2half2_rn(v.z * s, v.w * s);
  ((__half2*)hp)[loc * 2]     = h01;
  ((__half2*)hp)[loc * 2 + 1] = h23;
}

// ---------------- fp16 gather SpMM, paired (two independent SpMMs per launch) ----------------
// 4 lanes per row, each lane owns 16 halves (2x float4 per edge); unroll x4 ->
// 8 loads in flight per thread. perm is degree-DESCENDING (equal-degree waves).
// Epilogue: dst_h[row] = half(acc * post_h[row]); if HAS_SUM:
//   sum[row] += acc * post_sum[row] * 0.25   (final averaging folded in)

__device__ __forceinline__ void acc8(float* a, float4 v){
  union { float4 f; __half2 h[4]; } u;
  u.f = v;
#pragma unroll
  for (int k = 0; k < 4; ++k){
    float2 f = __half22float2(u.h[k]);
    a[2*k]     += f.x;
    a[2*k + 1] += f.y;
  }
}

template<bool HAS_SUM>
__global__ void spmm_pair(
    const int* __restrict__ offsA, const int* __restrict__ adjA, const int* __restrict__ permA,
    const __half* __restrict__ srcA, const float* __restrict__ psA, const float* __restrict__ phA,
    __half* __restrict__ dstA, float* __restrict__ sumA, int nA,
    const int* __restrict__ offsB, const int* __restrict__ adjB, const int* __restrict__ permB,
    const __half* __restrict__ srcB, const float* __restrict__ psB, const float* __restrict__ phB,
    __half* __restrict__ dstB, float* __restrict__ sumB, int nB){
  int t = blockIdx.x * blockDim.x + threadIdx.x;
  int rid = t >> 2;
  int lane = t & 3;
  const int* offs; const int* adj; const __half* src; const float* ps; const float* ph;
  __half* dst; float* sum; int row;
  if (rid < nA){
    row = permA[rid]; offs = offsA; adj = adjA; src = srcA; ps = psA; ph = phA; dst = dstA; sum = sumA;
  } else {
    rid -= nA;
    if (rid >= nB) return;
    row = permB[rid]; offs = offsB; adj = adjB; src = srcB; ps = psB; ph = phB; dst = dstB; sum = sumB;
  }
  int beg = offs[row], end = offs[row + 1];
  const size_t hoff = (size_t)(lane << 4);   // in halves: lane*16 (32 B)
  float acc[16];
#pragma unroll
  for (int k = 0; k < 16; ++k) acc[k] = 0.f;
  int j = beg;
  for (; j + 3 < end; j += 4){
    int n0 = adj[j], n1 = adj[j+1], n2 = adj[j+2], n3 = adj[j+3];
    const float4* p0 = (const float4*)(src + (((size_t)n0) << 6) + hoff);
    const float4* p1 = (const float4*)(src + (((size_t)n1) << 6) + hoff);
    const float4* p2 = (const float4*)(src + (((size_t)n2) << 6) + hoff);
    const float4* p3 = (const float4*)(src + (((size_t)n3) << 6) + hoff);
    float4 a0 = p0[0], a1 = p0[1];
    float4 b0 = p1[0], b1 = p1[1];
    float4 c0 = p2[0], c1 = p2[1];
    float4 d0 = p3[0], d1 = p3[1];
    acc8(acc, a0); acc8(acc + 8, a1);
    acc8(acc, b0); acc8(acc + 8, b1);
    acc8(acc, c0); acc8(acc + 8, c1);
    acc8(acc, d0); acc8(acc + 8, d1);
  }
  for (; j < end; ++j){
    int n0 = adj[j];
    const float4* p0 = (const float4*)(src + (((size_t)n0) << 6) + hoff);
    float4 a0 = p0[0], a1 = p0[1];
    acc8(acc, a0); acc8(acc + 8, a1);
  }
  float phv = ph[row];
  union { float4 f[2]; __half2 h[8]; } ob;
#pragma unroll
  for (int k = 0; k < 8; ++k)
    ob.h[k] = __floats2half2_rn(acc[2*k] * phv, acc[2*k + 1] * phv);
  float4* dp = (float4*)(dst + (((size_t)row) << 6) + hoff);
  dp[0] = ob.f[0];
  dp[1] = ob.f[1];
  if (HAS_SUM){
    float psv = ps[row] * 0.25f;
    float4* sp = (float4*)(sum + (((size_t)row) << 6) + (size_t)(lane << 4));
#pragma unroll
    for (int k = 0; k < 4; ++k){
      float4 s = sp[k];
      s.x += acc[4*k]     * psv;
      s.y += acc[4*k + 1] * psv;
      s.z += acc[4*k + 2] * psv;
      s.w += acc[4*k + 3] * psv;
      sp[k] = s;
    }
  }
}

// ---------------- driver ----------------

extern "C" void kernel_launch(void* const* d_in, const int* in_sizes, int n_in,
                              void* d_out, int out_size, void* d_ws, size_t ws_size,
                              hipStream_t stream){
  const float* user_emb = (const float*)d_in[0];
  const float* item_emb = (const float*)d_in[1];
  const int*   u_idx    = (const int*)d_in[2];
  const int*   i_idx    = (const int*)d_in[3];
  float* out = (float*)d_out;

  char* w = (char*)d_ws;
  size_t off = 0;
  auto alloc = [&](size_t bytes) -> void* {
    void* p = (void*)(w + off);
    off += (bytes + 255) & ~(size_t)255;
    return p;
  };
  int* cnt_u   = (int*)alloc((size_t)U_NUM * 4);
  int* cnt_i   = (int*)alloc((size_t)I_NUM * 4);
  int* offs_u  = (int*)alloc((size_t)(U_NUM + 1) * 4);
  int* offs_i  = (int*)alloc((size_t)(I_NUM + 1) * 4);
  int* cm_u    = (int*)alloc((size_t)NBLK_E * NBU_U * 4);
  int* cm_i    = (int*)alloc((size_t)NBLK_E * NBU_I * 4);
  int* bm_u    = (int*)alloc((size_t)NBLK_E * NBU_U * 4);
  int* bm_i    = (int*)alloc((size_t)NBLK_E * NBU_I * 4);
  int* tot_u   = (int*)alloc((size_t)NBU_U * 4);
  int* tot_i   = (int*)alloc((size_t)NBU_I * 4);
  int* boffs_u = (int*)alloc((size_t)(NBU_U + 1) * 4);
  int* boffs_i = (int*)alloc((size_t)(NBU_I + 1) * 4);
  int* scr_u   = (int*)alloc((size_t)NBU_U * 4);     // small_scan cur scratch
  int* scr_i   = (int*)alloc((size_t)NBU_I * 4);
  int* dhist_u = (int*)alloc((size_t)DBINS * 4);
  int* dhist_i = (int*)alloc((size_t)DBINS * 4);
  int* doffs_u = (int*)alloc((size_t)(DBINS + 1) * 4);
  int* doffs_i = (int*)alloc((size_t)(DBINS + 1) * 4);
  int* dcur_u  = (int*)alloc((size_t)DBINS * 4);
  int* dcur_i  = (int*)alloc((size_t)DBINS * 4);
  int* perm_u  = (int*)alloc((size_t)U_NUM * 4);
  int* perm_i  = (int*)alloc((size_t)I_NUM * 4);
  int* adj_u   = (int*)alloc((size_t)NE * 4);
  int* adj_i   = (int*)alloc((size_t)NE * 4);
  float* du_inv  = (float*)alloc((size_t)U_NUM * 4);
  float* du_invs = (float*)alloc((size_t)U_NUM * 4);
  float* di_inv  = (float*)alloc((size_t)I_NUM * 4);
  float* di_invs = (float*)alloc((size_t)I_NUM * 4);
  // half-table region, 38.4 MB; the packed bins (16 MB) alias its start and
  // are dead before init_k writes the half tables.
  __half* hreg = (__half*)alloc((size_t)(U_NUM + I_NUM) * 2 * EMB * 2);
  __half* ue_h    = hreg;                                  // U_NUM*64
  __half* ie_h    = ue_h    + (size_t)U_NUM * EMB;         // I_NUM*64
  __half* tmp_i_h = ie_h    + (size_t)I_NUM * EMB;         // I_NUM*64
  __half* tmp_u_h = tmp_i_h + (size_t)I_NUM * EMB;         // U_NUM*64
  int* bin_u = (int*)hreg;            // NE ints (8 MB)
  int* bin_i = bin_u + NE;            // NE ints (8 MB)

  // ---- CSR build (count-matrix radix sort) ----
  hipMemsetAsync(dhist_u, 0, (size_t)DBINS * 4, stream);
  hipMemsetAsync(dhist_i, 0, (size_t)DBINS * 4, stream);

  hist_k<<<NBLK_E, 256, 0, stream>>>(u_idx, i_idx, cm_u, cm_i);
  colsum_k<<<NBU_T, 256, 0, stream>>>(cm_u, cm_i, tot_u, tot_i);
  small_scan_k<<<1, 1024, 0, stream>>>(tot_u, boffs_u, scr_u, NBU_U);
  small_scan_k<<<1, 1024, 0, stream>>>(tot_i, boffs_i, scr_i, NBU_I);
  colscan_k<<<NBU_T, 256, 0, stream>>>(cm_u, cm_i, boffs_u, boffs_i, bm_u, bm_i);
  binfill_k<<<NBLK_E, 256, 0, stream>>>(u_idx, i_idx, bm_u, bm_i, bin_u, bin_i);
  bucket_build_k<<<NBU_T, 256, 0, stream>>>(bin_u, bin_i, boffs_u, boffs_i,
                                            cnt_u, cnt_i, offs_u, offs_i,
                                            du_inv, du_invs, di_inv, di_invs,
                                            adj_u, adj_i, dhist_u, dhist_i);

  // ---- degree sort (descending perm) ----
  small_scan_k<<<1, 1024, 0, stream>>>(dhist_u, doffs_u, dcur_u, DBINS);
  small_scan_k<<<1, 1024, 0, stream>>>(dhist_i, doffs_i, dcur_i, DBINS);
  deg_scatter_k<<<ceil_div(U_NUM, 2048), 256, 0, stream>>>(cnt_u, dcur_u, perm_u, U_NUM);
  deg_scatter_k<<<ceil_div(I_NUM, 2048), 256, 0, stream>>>(cnt_i, dcur_i, perm_i, I_NUM);

  // ---- propagation (fp16 tables, fp32 accumulation) ----
  init_k<<<ceil_div((U_NUM + I_NUM) * EMB / 4, 256), 256, 0, stream>>>(
      user_emb, item_emb, du_invs, di_invs, out, ue_h, ie_h);

  float* sum_u = out;
  float* sum_i = out + (size_t)U_NUM * EMB;
  const int pair_grid = ceil_div((U_NUM + I_NUM) * 4, 256);
  for (int l = 0; l < NLAYERS; ++l){
    // A: tmp_i_h = half(d_i_inv * R^T ue_h)   +   C: tmp_u_h = half(d_u_inv * R ie_h)
    spmm_pair<false><<<pair_grid, 256, 0, stream>>>(
        offs_i, adj_i, perm_i, ue_h, nullptr, di_inv, tmp_i_h, nullptr, I_NUM,
        offs_u, adj_u, perm_u, ie_h, nullptr, du_inv, tmp_u_h, nullptr, U_NUM);
    // B: sum_u += 0.25*du_invs * R tmp_i_h ; ue_h = half(du_inv * R tmp_i_h)
    // D: sum_i += 0.25*di_invs * R^T tmp_u_h ; ie_h = half(di_inv * R^T tmp_u_h)
    spmm_pair<true><<<pair_grid, 256, 0, stream>>>(
        offs_u, adj_u, perm_u, tmp_i_h, du_invs, du_inv, ue_h, sum_u, U_NUM,
        offs_i, adj_i, perm_i, tmp_u_h, di_invs, di_inv, ie_h, sum_i, I_NUM);
  }
}